// Round 1
// 133.701 us; speedup vs baseline: 1.0293x; 1.0293x over previous
//
#include <hip/hip_runtime.h>
#include <hip/hip_bf16.h>

// DenseAttention — reassociated (6.44 GF vs 155 GF direct), bf16 MFMA.
// Round 16: r15 chain + two one-time passes that kill redundant traffic:
//   cvt:   xbf = bf16(x) once (24 MB) — gram/out staged x in f32 and paid
//          f2bf VALU in the latency-exposed stagers; now ushort loads.
//   gram:  Gp[s][bq][f][h] = x_f . x_h     grid(4,8,8)=256, 128-tiles (bf16 x)
//   gred:  Gsum[bq] = sum_s Gp[s][bq] once in f32 (18 MB) — 2a previously
//          re-did the 8-way sum under all 16 consuming tiles (288 MB L2/L3).
//   2a:    Tt[ba][g][qf] = comb_g . Gsum_f  grid(16,32)=512, bf16 out
//   2b:    Wt[ba][g][e] += Tt_g . qw_e      grid(16,8,4)=512, split-K4, atomic
//   out:   out[t][ag]   = xbf_t . Wt_g      grid(128,8)=1024
// Fragment-major LDS -> conflict-free ds_read_b128 fragment reads.
// ws (32 MB): Gp 16 | Wt 2 | Tt(bf16) 4 | Gsum 2 | xbf(bf16) 8.

typedef unsigned short u16;
using short8  = __attribute__((ext_vector_type(8))) short;
using floatx4 = __attribute__((ext_vector_type(4))) float;

__device__ inline u16 f2bf(float f) {               // RNE f32->bf16
    unsigned u = __float_as_uint(f);
    unsigned r = u + 0x7fffu + ((u >> 16) & 1u);
    return (u16)(r >> 16);
}

// ---------------- 64-row stagers (2a/2b/out bodies — r13-verbatim) ----------
// Row-major source [64 m][64 k] -> fragment-major LDS (MT=4).
template <typename T>
__device__ inline void stage64(const T* __restrict__ src, long ld,
                               u16* __restrict__ dst, int tid) {
#pragma unroll
    for (int it = 0; it < 4; ++it) {
        const int flat = (it * 256 + tid) * 4;
        const int kl = flat & 63, rl = flat >> 6;
        ushort4 v;
        if (sizeof(T) == 4) {
            const float4 f = *(const float4*)&((const float*)src)[(long)rl * ld + kl];
            v.x = f2bf(f.x); v.y = f2bf(f.y); v.z = f2bf(f.z); v.w = f2bf(f.w);
        } else {
            v = *(const ushort4*)&((const u16*)src)[(long)rl * ld + kl];
        }
        const int chunk = ((kl >> 5) * 4 + (rl >> 4)) * 64 + ((kl >> 3) & 3) * 16 + (rl & 15);
        *(ushort4*)&dst[chunk * 8 + (kl & 7)] = v;
    }
}

// Same, source = f32 sum of 8 partial arrays spaced partStride apart.
// (kept: referenced by the BSUM8 template branch)
__device__ inline void stage64_sum8(const float* __restrict__ s0, long ld,
                                    long partStride,
                                    u16* __restrict__ dst, int tid) {
#pragma unroll
    for (int it = 0; it < 4; ++it) {
        const int flat = (it * 256 + tid) * 4;
        const int kl = flat & 63, rl = flat >> 6;
        const long off = (long)rl * ld + kl;
        float4 acc = *(const float4*)&s0[off];
#pragma unroll
        for (int s = 1; s < 8; ++s) {
            const float4 f = *(const float4*)&s0[(long)s * partStride + off];
            acc.x += f.x; acc.y += f.y; acc.z += f.z; acc.w += f.w;
        }
        ushort4 v;
        v.x = f2bf(acc.x); v.y = f2bf(acc.y); v.z = f2bf(acc.z); v.w = f2bf(acc.w);
        const int chunk = ((kl >> 5) * 4 + (rl >> 4)) * 64 + ((kl >> 3) & 3) * 16 + (rl & 15);
        *(ushort4*)&dst[chunk * 8 + (kl & 7)] = v;
    }
}

// K-major f32 source [64 k][64 m] -> fragment-major LDS (scatter; verified).
__device__ inline void stage_km64(const float* __restrict__ src, long ld,
                                  u16* __restrict__ dst, int tid) {
#pragma unroll
    for (int it = 0; it < 4; ++it) {
        const int flat = (it * 256 + tid) * 4;
        const int m = flat & 63, k = flat >> 6;
        const float4 f = *(const float4*)&src[(long)k * ld + m];
        const int cb_ = ((k >> 5) * 4 + (m >> 4)) * 64 + ((k & 31) >> 3) * 16 + (m & 15);
        const int j = k & 7;
        dst[(cb_ + 0) * 8 + j] = f2bf(f.x);
        dst[(cb_ + 1) * 8 + j] = f2bf(f.y);
        dst[(cb_ + 2) * 8 + j] = f2bf(f.z);
        dst[(cb_ + 3) * 8 + j] = f2bf(f.w);
    }
}

// 64-tile GEMM body (r13-verbatim): K=256 one burst, one sync.
template <typename TA, typename TB, typename TC,
          bool AKM, bool BKM, bool BSUM8, bool ATOMIC>
__device__ inline void gemm_tile(const TA* __restrict__ A, long lda,
                                 const TB* __restrict__ B, long ldb,
                                 long partStride,
                                 TC* __restrict__ C, long ldc,
                                 int m0, int n0) {
    __shared__ u16 As[16384];   // 32 KB: 4 x 64-k fragment blocks
    __shared__ u16 Bs[16384];
    const int tid = threadIdx.x, lane = tid & 63, w = tid >> 6;
    const int IA = (w & 1) * 2, JB = (w >> 1) * 2;
    floatx4 acc[2][2] = {};

#pragma unroll
    for (int kb = 0; kb < 4; ++kb) {
        if (AKM) stage_km64((const float*)A + (long)(kb * 64) * lda, lda, As + kb * 4096, tid);
        else     stage64(A + kb * 64, lda, As + kb * 4096, tid);
    }
#pragma unroll
    for (int kb = 0; kb < 4; ++kb) {
        if (BSUM8)    stage64_sum8((const float*)B + kb * 64, ldb, partStride, Bs + kb * 4096, tid);
        else if (BKM) stage_km64((const float*)B + (long)(kb * 64) * ldb, ldb, Bs + kb * 4096, tid);
        else          stage64(B + kb * 64, ldb, Bs + kb * 4096, tid);
    }
    __syncthreads();

#pragma unroll
    for (int kb = 0; kb < 4; ++kb)
#pragma unroll
        for (int s = 0; s < 2; ++s) {
            short8 af[2], bfr[2];
#pragma unroll
            for (int i = 0; i < 2; ++i)
                af[i] = *(const short8*)&As[kb * 4096 + ((s * 4 + IA + i) * 64 + lane) * 8];
#pragma unroll
            for (int j = 0; j < 2; ++j)
                bfr[j] = *(const short8*)&Bs[kb * 4096 + ((s * 4 + JB + j) * 64 + lane) * 8];
#pragma unroll
            for (int i = 0; i < 2; ++i)
#pragma unroll
                for (int j = 0; j < 2; ++j)
                    acc[i][j] = __builtin_amdgcn_mfma_f32_16x16x32_bf16(af[i], bfr[j], acc[i][j], 0, 0, 0);
        }

    const int rb = (lane >> 4) * 4, col = lane & 15;
#pragma unroll
    for (int i = 0; i < 2; ++i)
#pragma unroll
        for (int j = 0; j < 2; ++j)
#pragma unroll
            for (int r = 0; r < 4; ++r) {
                const int gm = m0 + (IA + i) * 16 + rb + r;
                const int gn = n0 + (JB + j) * 16 + col;
                TC* p = &C[(long)gm * ldc + gn];
                if (sizeof(TC) == 2) *(u16*)p = f2bf(acc[i][j][r]);
                else if (ATOMIC) atomicAdd((float*)p, acc[i][j][r]);
                else *(float*)p = acc[i][j][r];
            }
}

// ---------------- one-time passes -------------------------------------------
// xbf = bf16(x), row-major, 4,194,304 elements. grid 2048.
__global__ __launch_bounds__(256) void k_cvt(const float* __restrict__ x,
                                             u16* __restrict__ xbf) {
    const long i = ((long)blockIdx.x * 256 + threadIdx.x) * 8;
    const float4 a = *(const float4*)&x[i];
    const float4 b = *(const float4*)&x[i + 4];
    ushort4 lo, hi;
    lo.x = f2bf(a.x); lo.y = f2bf(a.y); lo.z = f2bf(a.z); lo.w = f2bf(a.w);
    hi.x = f2bf(b.x); hi.y = f2bf(b.y); hi.z = f2bf(b.z); hi.w = f2bf(b.w);
    *(ushort4*)&xbf[i]     = lo;
    *(ushort4*)&xbf[i + 4] = hi;
}

// Gsum[bq][f][h] = sum_s Gp[s][bq][f][h], f32. 524288 floats, grid 512.
__global__ __launch_bounds__(256) void k_gred(const float* __restrict__ Gp,
                                              float* __restrict__ Gs) {
    const long i = ((long)blockIdx.x * 256 + threadIdx.x) * 4;
    float4 acc = *(const float4*)&Gp[i];
#pragma unroll
    for (int s = 1; s < 8; ++s) {
        const float4 f = *(const float4*)&Gp[(long)s * 524288 + i];
        acc.x += f.x; acc.y += f.y; acc.z += f.z; acc.w += f.w;
    }
    *(float4*)&Gs[i] = acc;
}

// ---------------- gram: 128x128 tile, bf16 source ----------------------------
// K-major bf16 [64 k][128 m] -> 128-row fragment-major block (8192 u16 = 16 KB).
// Element (m,k): lane=((k&31)>>3)*16+(m&15), chunk=((k>>5)*8+(m>>4))*64+lane.
__device__ inline void stage_km128_bf(const u16* __restrict__ src, long ld,
                                      u16* __restrict__ dst, int tid) {
#pragma unroll
    for (int it = 0; it < 4; ++it) {
        const int flat = (it * 256 + tid) * 8;
        const int m = flat & 127, k = flat >> 7;
        const short8 v = *(const short8*)&src[(long)k * ld + m];
        const int cb_ = ((k >> 5) * 8 + (m >> 4)) * 64 + ((k & 31) >> 3) * 16 + (m & 15);
        const int j = k & 7;
#pragma unroll
        for (int e = 0; e < 8; ++e)
            dst[(cb_ + e) * 8 + j] = (u16)v[e];
    }
}

// Gp[split][bq][f][h] = sum_{u in split} x[b][u][qf] * x[b][u][qh]
// 128x128 tile, two K=128 bursts (64 MFMA/wave/burst), non-atomic.
// Also zeroes this block's 8KB slice of Wt (256 blocks x 2048 floats = 2 MB).
__global__ __launch_bounds__(256) void k_gram(const u16* __restrict__ xbf,
                                              float* __restrict__ Gp,
                                              float* __restrict__ Wt) {
    __shared__ u16 As[16384];   // 32 KB: 2 x (128m x 64k) fragment blocks
    __shared__ u16 Bs[16384];
    const int tl = blockIdx.x, bq = blockIdx.y, split = blockIdx.z;
    const int tm = tl >> 1, tn = tl & 1;
    const int b = bq >> 2, q = bq & 3;
    const int tid = threadIdx.x, lane = tid & 63, w = tid >> 6;
    const int IA2 = (w & 1), JB2 = (w >> 1);     // wave's 64x64 quadrant

    {   // zero Wt: 256 blocks x 2048 floats
        const int bl = tl + 4 * bq + 32 * split;
        float4 zero = {0.f, 0.f, 0.f, 0.f};
        float4* wz = (float4*)(Wt + (long)bl * 2048) + tid;
        wz[0] = zero; wz[256] = zero;
    }

    const u16* base = xbf + (long)b * 2097152 + (long)split * 256 * 1024 + q * 256;
    const u16* A = base + tm * 128;    // [k=u][m=f], ld 1024
    const u16* B = base + tn * 128;
    floatx4 acc[4][4] = {};

#pragma unroll
    for (int burst = 0; burst < 2; ++burst) {
        if (burst) __syncthreads();
#pragma unroll
        for (int kb = 0; kb < 2; ++kb) {
            const long kk = burst * 128 + kb * 64;
            stage_km128_bf(A + kk * 1024, 1024, As + kb * 8192, tid);
            stage_km128_bf(B + kk * 1024, 1024, Bs + kb * 8192, tid);
        }
        __syncthreads();
#pragma unroll
        for (int kb = 0; kb < 2; ++kb)
#pragma unroll
            for (int s = 0; s < 2; ++s) {
                short8 af[4], bfr[4];
#pragma unroll
                for (int i = 0; i < 4; ++i)
                    af[i] = *(const short8*)&As[kb * 8192 + ((s * 8 + IA2 * 4 + i) * 64 + lane) * 8];
#pragma unroll
                for (int j = 0; j < 4; ++j)
                    bfr[j] = *(const short8*)&Bs[kb * 8192 + ((s * 8 + JB2 * 4 + j) * 64 + lane) * 8];
#pragma unroll
                for (int i = 0; i < 4; ++i)
#pragma unroll
                    for (int j = 0; j < 4; ++j)
                        acc[i][j] = __builtin_amdgcn_mfma_f32_16x16x32_bf16(af[i], bfr[j], acc[i][j], 0, 0, 0);
            }
    }

    float* C = Gp + (long)(split * 8 + bq) * 65536;
    const int rb = (lane >> 4) * 4, col = lane & 15;
#pragma unroll
    for (int i = 0; i < 4; ++i)
#pragma unroll
        for (int j = 0; j < 4; ++j)
#pragma unroll
            for (int r = 0; r < 4; ++r) {
                const int gm = tm * 128 + IA2 * 64 + i * 16 + rb + r;
                const int gn = tn * 128 + JB2 * 64 + j * 16 + col;
                C[(long)gm * 256 + gn] = acc[i][j][r];
            }
}

// 2a: Tt[ba][g][q*256+f] = sum_h comb[a][q*256+h][g] * Gsum[bq][f][h]
__global__ __launch_bounds__(256) void k_2a(const float* __restrict__ comb,
                                            const float* __restrict__ Gs,
                                            u16* __restrict__ Tt) {
    const int tile = blockIdx.x, i = blockIdx.y;     // i = ba*4+q
    const int tm = tile >> 2, tn = tile & 3;
    const int q = i & 3, ba = i >> 2, b = ba >> 2, a = ba & 3;
    gemm_tile<float, float, u16, true, false, false, false>(
        comb + (long)a * 262144 + (long)q * 256 * 256 + tm * 64, 256,
        Gs + (long)(b * 4 + q) * 65536 + (long)tn * 64 * 256, 256,
        0,
        Tt + (long)ba * 262144, 1024,
        tm * 64, q * 256 + tn * 64);
}

// 2b: Wt[ba][g][e] += sum_{k in split} Tt[ba][g][k] * qw[a][e][k]
__global__ __launch_bounds__(256) void k_2b(const u16* __restrict__ Tt,
                                            const float* __restrict__ qw,
                                            float* __restrict__ Wt) {
    const int tile = blockIdx.x, ba = blockIdx.y, split = blockIdx.z;
    const int tm = tile >> 2, tn = tile & 3;
    const int a = ba & 3;
    gemm_tile<u16, float, float, false, false, false, true>(
        Tt + (long)ba * 262144 + (long)tm * 64 * 1024 + split * 256, 1024,
        qw + (long)a * 262144 + (long)tn * 64 * 1024 + split * 256, 1024, 0,
        Wt + (long)ba * 65536, 256,
        tm * 64, tn * 64);
}

// out: out[b][t][a*256+g] = sum_e xbf[b][t][a*256+e] * Wt[ba][g][e]
__global__ __launch_bounds__(256) void k_3(const u16* __restrict__ xbf,
                                           const float* __restrict__ Wt,
                                           float* __restrict__ out) {
    const int tl = blockIdx.x, ba = blockIdx.y;      // tl: tm 0..31, tn 0..3
    const int tm = tl >> 2, tn = tl & 3;
    const int b = ba >> 2, a = ba & 3;
    gemm_tile<u16, float, float, false, false, false, false>(
        xbf + (long)b * 2097152 + (long)tm * 64 * 1024 + a * 256, 1024,
        Wt + (long)ba * 65536 + (long)tn * 64 * 256, 256, 0,
        out + (long)b * 2097152 + a * 256, 1024,
        tm * 64, tn * 64);
}

extern "C" void kernel_launch(void* const* d_in, const int* in_sizes, int n_in,
                              void* d_out, int out_size, void* d_ws, size_t ws_size,
                              hipStream_t stream) {
    const float* x    = (const float*)d_in[0];   // [2,2048,1024]
    const float* qw   = (const float*)d_in[1];   // [4,256,1024]
    const float* comb = (const float*)d_in[2];   // [4,1024,256]
    float* out = (float*)d_out;

    char* ws = (char*)d_ws;
    float* Gp = (float*)(ws);                    // 16 MB [8 split][8 bq][256x256]
    float* Wt = (float*)(ws + (16u << 20));      // 2 MB  [8][256][256]  Wt[g][e]
    u16*   Tt = (u16*)  (ws + (18u << 20));      // 4 MB  [8][256][1024] Tt[g][qf] bf16
    float* Gs = (float*)(ws + (22u << 20));      // 2 MB  [8 bq][256x256] f32
    u16*   xbf= (u16*)  (ws + (24u << 20));      // 8 MB  [2][2048][1024] bf16

    k_cvt <<<dim3(2048),     256, 0, stream>>>(x, xbf);
    k_gram<<<dim3(4, 8, 8),  256, 0, stream>>>(xbf, Gp, Wt);
    k_gred<<<dim3(512),      256, 0, stream>>>(Gp, Gs);
    k_2a  <<<dim3(16, 32),   256, 0, stream>>>(comb, Gs, Tt);
    k_2b  <<<dim3(16, 8, 4), 256, 0, stream>>>(Tt, qw, Wt);
    k_3   <<<dim3(128, 8),   256, 0, stream>>>(xbf, Wt, out);
}

// Round 3
// 132.071 us; speedup vs baseline: 1.0420x; 1.0123x over previous
//
#include <hip/hip_runtime.h>
#include <hip/hip_bf16.h>

// DenseAttention — reassociated (6.44 GF vs 155 GF direct), bf16 MFMA.
// Round 17 (resubmit — r1 bench hit GPUAcquisitionTimeout, never ran).
// All-bf16 staging. r16 post-mortem: intermediates are L2/L3-served,
// chain is staging-instruction/latency-bound, not BW-bound. So: every GEMM
// operand is pre-converted to bf16 row-major once, and the tile stager becomes
// 2x{16B global load + 16B ds_write_b128} per thread (was f2bf + up to 64
// scalar ds_write_b16). k_2b de-atomicized (full-K blocks, bf16 Wt out).
//   prep:  xbf = bf16(x) | qwbf = bf16(qw) | combt = bf16(comb^T)   grid 2816
//   gram:  Gp[s][bq][f][h] = x_f . x_h     grid(4,8,8)=256, 128-tiles (bf16 x)
//   gred:  Gsbf[bq] = bf16(sum_s Gp[s][bq])  grid 512
//   2a:    Tt[ba][g][qf] = combt_g . Gsbf_f  grid(16,32)=512, bf16 out
//   2b:    Wtbf[ba][g][e] = Tt_g . qwbf_e    grid(16,8)=128, K=1024 in-block,
//          non-atomic (was split-K4 atomic: 2.1M f32 atomicAdds deleted)
//   out:   out[t][ag]   = xbf_t . Wtbf_g     grid(128,8)=1024
// Fragment-major LDS -> conflict-free ds_read_b128 fragment reads.
// ws (34 MB): Gp 16 | xbf 8 | Tt 4 | qwbf 2 | combt 2 | Gsbf 1 | Wtbf 1.

typedef unsigned short u16;
using short8  = __attribute__((ext_vector_type(8))) short;
using floatx4 = __attribute__((ext_vector_type(4))) float;

__device__ inline u16 f2bf(float f) {               // RNE f32->bf16
    unsigned u = __float_as_uint(f);
    unsigned r = u + 0x7fffu + ((u >> 16) & 1u);
    return (u16)(r >> 16);
}

// bf16 row-major [64 m][64 k] -> fragment-major LDS.
// Per thread: 2 x (global_load_dwordx4 + ds_write_b128). kl%8==0 so the 8
// k-elems land contiguously in one chunk (j=0..7).
__device__ inline void stage64_bf(const u16* __restrict__ src, long ld,
                                  u16* __restrict__ dst, int tid) {
#pragma unroll
    for (int it = 0; it < 2; ++it) {
        const int flat = (it * 256 + tid) * 8;
        const int kl = flat & 63, rl = flat >> 6;
        const short8 v = *(const short8*)&src[(long)rl * ld + kl];
        const int chunk = ((kl >> 5) * 4 + (rl >> 4)) * 64 + ((kl >> 3) & 3) * 16 + (rl & 15);
        *(short8*)&dst[chunk * 8] = v;
    }
}

// 64x64-tile GEMM body, all-bf16 operands, KR sequential rounds of K=256.
template <typename TC, int KR>
__device__ inline void gemm64(const u16* __restrict__ A, long lda,
                              const u16* __restrict__ B, long ldb,
                              TC* __restrict__ C, long ldc,
                              int m0, int n0) {
    __shared__ u16 As[16384];   // 32 KB: 4 x 64-k fragment blocks
    __shared__ u16 Bs[16384];
    const int tid = threadIdx.x, lane = tid & 63, w = tid >> 6;
    const int IA = (w & 1) * 2, JB = (w >> 1) * 2;
    floatx4 acc[2][2] = {};

#pragma unroll
    for (int r = 0; r < KR; ++r) {
        if (r) __syncthreads();               // protect LDS reuse
        const u16* Ar = A + r * 256;
        const u16* Br = B + r * 256;
#pragma unroll
        for (int kb = 0; kb < 4; ++kb) {
            stage64_bf(Ar + kb * 64, lda, As + kb * 4096, tid);
            stage64_bf(Br + kb * 64, ldb, Bs + kb * 4096, tid);
        }
        __syncthreads();

#pragma unroll
        for (int kb = 0; kb < 4; ++kb)
#pragma unroll
            for (int s = 0; s < 2; ++s) {
                short8 af[2], bfr[2];
#pragma unroll
                for (int i = 0; i < 2; ++i)
                    af[i] = *(const short8*)&As[kb * 4096 + ((s * 4 + IA + i) * 64 + lane) * 8];
#pragma unroll
                for (int j = 0; j < 2; ++j)
                    bfr[j] = *(const short8*)&Bs[kb * 4096 + ((s * 4 + JB + j) * 64 + lane) * 8];
#pragma unroll
                for (int i = 0; i < 2; ++i)
#pragma unroll
                    for (int j = 0; j < 2; ++j)
                        acc[i][j] = __builtin_amdgcn_mfma_f32_16x16x32_bf16(af[i], bfr[j], acc[i][j], 0, 0, 0);
            }
    }

    const int rb = (lane >> 4) * 4, col = lane & 15;
#pragma unroll
    for (int i = 0; i < 2; ++i)
#pragma unroll
        for (int j = 0; j < 2; ++j)
#pragma unroll
            for (int r = 0; r < 4; ++r) {
                const int gm = m0 + (IA + i) * 16 + rb + r;
                const int gn = n0 + (JB + j) * 16 + col;
                TC* p = &C[(long)gm * ldc + gn];
                if (sizeof(TC) == 2) *(u16*)p = f2bf(acc[i][j][r]);
                else                 *(float*)p = acc[i][j][r];
            }
}

// ---------------- prep: xbf | qwbf | combt (transpose) -----------------------
__global__ __launch_bounds__(256) void k_prep(const float* __restrict__ x,
                                              const float* __restrict__ qw,
                                              const float* __restrict__ comb,
                                              u16* __restrict__ xbf,
                                              u16* __restrict__ qwbf,
                                              u16* __restrict__ combt) {
    const int bx = blockIdx.x, tid = threadIdx.x;
    __shared__ u16 T[64][66];
    if (bx < 2560) {                        // flat bf16 conversions
        const float* src = bx < 2048 ? x : qw;
        u16* dst = bx < 2048 ? xbf : qwbf;
        const long i = ((long)(bx < 2048 ? bx : bx - 2048) * 256 + tid) * 8;
        const float4 a = *(const float4*)&src[i];
        const float4 b = *(const float4*)&src[i + 4];
        ushort4 lo, hi;
        lo.x = f2bf(a.x); lo.y = f2bf(a.y); lo.z = f2bf(a.z); lo.w = f2bf(a.w);
        hi.x = f2bf(b.x); hi.y = f2bf(b.y); hi.z = f2bf(b.z); hi.w = f2bf(b.w);
        *(ushort4*)&dst[i]     = lo;
        *(ushort4*)&dst[i + 4] = hi;
    } else {                                // combt[a][g][qh] = comb[a][qh][g]
        const int t = bx - 2560;            // 256 blocks: 4 a x 16 qh x 4 g
        const int a = t >> 6;
        const int qh0 = ((t >> 2) & 15) * 64, g0 = (t & 3) * 64;
        const float* src = comb + (long)a * 262144;   // [1024 qh][256 g]
        u16* dst = combt + (long)a * 262144;          // [256 g][1024 qh]
#pragma unroll
        for (int it = 0; it < 4; ++it) {
            const int flat = (it * 256 + tid) * 4;
            const int r = flat >> 6, c = flat & 63;
            const float4 f = *(const float4*)&src[(long)(qh0 + r) * 256 + g0 + c];
            T[r][c]     = f2bf(f.x); T[r][c + 1] = f2bf(f.y);
            T[r][c + 2] = f2bf(f.z); T[r][c + 3] = f2bf(f.w);
        }
        __syncthreads();
#pragma unroll
        for (int it = 0; it < 4; ++it) {
            const int flat = (it * 256 + tid) * 4;
            const int r = flat >> 6, c = flat & 63;
            ushort4 v;
            v.x = T[c][r]; v.y = T[c + 1][r]; v.z = T[c + 2][r]; v.w = T[c + 3][r];
            *(ushort4*)&dst[(long)(g0 + r) * 1024 + qh0 + c] = v;
        }
    }
}

// Gsbf[bq][f][h] = bf16(sum_s Gp[s][bq][f][h]). 524288 elems, grid 512.
__global__ __launch_bounds__(256) void k_gred(const float* __restrict__ Gp,
                                              u16* __restrict__ Gs) {
    const long i = ((long)blockIdx.x * 256 + threadIdx.x) * 4;
    float4 acc = *(const float4*)&Gp[i];
#pragma unroll
    for (int s = 1; s < 8; ++s) {
        const float4 f = *(const float4*)&Gp[(long)s * 524288 + i];
        acc.x += f.x; acc.y += f.y; acc.z += f.z; acc.w += f.w;
    }
    ushort4 v;
    v.x = f2bf(acc.x); v.y = f2bf(acc.y); v.z = f2bf(acc.z); v.w = f2bf(acc.w);
    *(ushort4*)&Gs[i] = v;
}

// ---------------- gram: 128x128 tile, bf16 source ----------------------------
// K-major bf16 [64 k][128 m] -> 128-row fragment-major block (8192 u16 = 16 KB).
__device__ inline void stage_km128_bf(const u16* __restrict__ src, long ld,
                                      u16* __restrict__ dst, int tid) {
#pragma unroll
    for (int it = 0; it < 4; ++it) {
        const int flat = (it * 256 + tid) * 8;
        const int m = flat & 127, k = flat >> 7;
        const short8 v = *(const short8*)&src[(long)k * ld + m];
        const int cb_ = ((k >> 5) * 8 + (m >> 4)) * 64 + ((k & 31) >> 3) * 16 + (m & 15);
        const int j = k & 7;
#pragma unroll
        for (int e = 0; e < 8; ++e)
            dst[(cb_ + e) * 8 + j] = (u16)v[e];
    }
}

// Gp[split][bq][f][h] = sum_{u in split} x[b][u][qf] * x[b][u][qh]
// 128x128 tile, two K=128 bursts (64 MFMA/wave/burst), non-atomic.
__global__ __launch_bounds__(256) void k_gram(const u16* __restrict__ xbf,
                                              float* __restrict__ Gp) {
    __shared__ u16 As[16384];   // 32 KB: 2 x (128m x 64k) fragment blocks
    __shared__ u16 Bs[16384];
    const int tl = blockIdx.x, bq = blockIdx.y, split = blockIdx.z;
    const int tm = tl >> 1, tn = tl & 1;
    const int b = bq >> 2, q = bq & 3;
    const int tid = threadIdx.x, lane = tid & 63, w = tid >> 6;
    const int IA2 = (w & 1), JB2 = (w >> 1);     // wave's 64x64 quadrant

    const u16* base = xbf + (long)b * 2097152 + (long)split * 256 * 1024 + q * 256;
    const u16* A = base + tm * 128;    // [k=u][m=f], ld 1024
    const u16* B = base + tn * 128;
    floatx4 acc[4][4] = {};

#pragma unroll
    for (int burst = 0; burst < 2; ++burst) {
        if (burst) __syncthreads();
#pragma unroll
        for (int kb = 0; kb < 2; ++kb) {
            const long kk = burst * 128 + kb * 64;
            stage_km128_bf(A + kk * 1024, 1024, As + kb * 8192, tid);
            stage_km128_bf(B + kk * 1024, 1024, Bs + kb * 8192, tid);
        }
        __syncthreads();
#pragma unroll
        for (int kb = 0; kb < 2; ++kb)
#pragma unroll
            for (int s = 0; s < 2; ++s) {
                short8 af[4], bfr[4];
#pragma unroll
                for (int i = 0; i < 4; ++i)
                    af[i] = *(const short8*)&As[kb * 8192 + ((s * 8 + IA2 * 4 + i) * 64 + lane) * 8];
#pragma unroll
                for (int j = 0; j < 4; ++j)
                    bfr[j] = *(const short8*)&Bs[kb * 8192 + ((s * 8 + JB2 * 4 + j) * 64 + lane) * 8];
#pragma unroll
                for (int i = 0; i < 4; ++i)
#pragma unroll
                    for (int j = 0; j < 4; ++j)
                        acc[i][j] = __builtin_amdgcn_mfma_f32_16x16x32_bf16(af[i], bfr[j], acc[i][j], 0, 0, 0);
            }
    }

    float* C = Gp + (long)(split * 8 + bq) * 65536;
    const int rb = (lane >> 4) * 4, col = lane & 15;
#pragma unroll
    for (int i = 0; i < 4; ++i)
#pragma unroll
        for (int j = 0; j < 4; ++j)
#pragma unroll
            for (int r = 0; r < 4; ++r) {
                const int gm = tm * 128 + IA2 * 64 + i * 16 + rb + r;
                const int gn = tn * 128 + JB2 * 64 + j * 16 + col;
                C[(long)gm * 256 + gn] = acc[i][j][r];
            }
}

// 2a: Tt[ba][g][q*256+f] = sum_h combt[a][g][q*256+h] * Gsbf[bq][f][h]
__global__ __launch_bounds__(256) void k_2a(const u16* __restrict__ combt,
                                            const u16* __restrict__ Gs,
                                            u16* __restrict__ Tt) {
    const int tile = blockIdx.x, i = blockIdx.y;     // i = ba*4+q
    const int tm = tile >> 2, tn = tile & 3;
    const int q = i & 3, ba = i >> 2, b = ba >> 2, a = ba & 3;
    gemm64<u16, 1>(
        combt + (long)a * 262144 + (long)tm * 64 * 1024 + q * 256, 1024,
        Gs + (long)(b * 4 + q) * 65536 + (long)tn * 64 * 256, 256,
        Tt + (long)ba * 262144, 1024,
        tm * 64, q * 256 + tn * 64);
}

// 2b: Wtbf[ba][g][e] = sum_k Tt[ba][g][k] * qwbf[a][e][k], K=1024 in-block.
__global__ __launch_bounds__(256) void k_2b(const u16* __restrict__ Tt,
                                            const u16* __restrict__ qwbf,
                                            u16* __restrict__ Wt) {
    const int tile = blockIdx.x, ba = blockIdx.y;
    const int tm = tile >> 2, tn = tile & 3;
    const int a = ba & 3;
    gemm64<u16, 4>(
        Tt + (long)ba * 262144 + (long)tm * 64 * 1024, 1024,
        qwbf + (long)a * 262144 + (long)tn * 64 * 1024, 1024,
        Wt + (long)ba * 65536, 256,
        tm * 64, tn * 64);
}

// out: out[b][t][a*256+g] = sum_e xbf[b][t][a*256+e] * Wtbf[ba][g][e]
__global__ __launch_bounds__(256) void k_3(const u16* __restrict__ xbf,
                                           const u16* __restrict__ Wt,
                                           float* __restrict__ out) {
    const int tl = blockIdx.x, ba = blockIdx.y;      // tl: tm 0..31, tn 0..3
    const int tm = tl >> 2, tn = tl & 3;
    const int b = ba >> 2, a = ba & 3;
    gemm64<float, 1>(
        xbf + (long)b * 2097152 + (long)tm * 64 * 1024 + a * 256, 1024,
        Wt + (long)ba * 65536 + (long)tn * 64 * 256, 256,
        out + (long)b * 2097152 + a * 256, 1024,
        tm * 64, tn * 64);
}

extern "C" void kernel_launch(void* const* d_in, const int* in_sizes, int n_in,
                              void* d_out, int out_size, void* d_ws, size_t ws_size,
                              hipStream_t stream) {
    const float* x    = (const float*)d_in[0];   // [2,2048,1024]
    const float* qw   = (const float*)d_in[1];   // [4,256,1024]
    const float* comb = (const float*)d_in[2];   // [4,1024,256]
    float* out = (float*)d_out;

    char* ws = (char*)d_ws;
    float* Gp   = (float*)(ws);                  // 16 MB [8 split][8 bq][256x256]
    u16*   xbf  = (u16*)  (ws + (16u << 20));    //  8 MB [2][2048][1024] bf16
    u16*   Tt   = (u16*)  (ws + (24u << 20));    //  4 MB [8][256][1024] bf16
    u16*   qwbf = (u16*)  (ws + (28u << 20));    //  2 MB [4][256][1024] bf16
    u16*   combt= (u16*)  (ws + (30u << 20));    //  2 MB [4][256][1024] bf16 (comb^T)
    u16*   Gsbf = (u16*)  (ws + (32u << 20));    //  1 MB [8 bq][256][256] bf16
    u16*   Wtbf = (u16*)  (ws + (33u << 20));    //  1 MB [8][256][256] bf16

    k_prep<<<dim3(2816),    256, 0, stream>>>(x, qw, comb, xbf, qwbf, combt);
    k_gram<<<dim3(4, 8, 8), 256, 0, stream>>>(xbf, Gp);
    k_gred<<<dim3(512),     256, 0, stream>>>(Gp, Gsbf);
    k_2a  <<<dim3(16, 32),  256, 0, stream>>>(combt, Gsbf, Tt);
    k_2b  <<<dim3(16, 8),   256, 0, stream>>>(Tt, qwbf, Wtbf);
    k_3   <<<dim3(128, 8),  256, 0, stream>>>(xbf, Wtbf, out);
}